// Round 17
// baseline (82.721 us; speedup 1.0000x reference)
//
#include <hip/hip_runtime.h>
#include <cmath>

namespace {
constexpr int Cc = 256, CKc = 32, CVc = 32, KKc = 9;
constexpr int Bc = 8, Hc = 128, Wc = 128, HWc = Hc * Wc;

typedef __attribute__((ext_vector_type(8))) short   s16x8;
typedef __attribute__((ext_vector_type(8))) __bf16  bf16x8;
typedef __attribute__((ext_vector_type(4))) float   f32x4;

__device__ inline unsigned short f2bf(float f) {   // RNE f32 -> bf16 bits
    union { float f; unsigned u; } v; v.f = f;
    unsigned u = v.u + 0x7fffu + ((v.u >> 16) & 1u);
    return (unsigned short)(u >> 16);
}
__device__ inline float bf2f(unsigned short u) {
    union { unsigned u; float f; } v; v.u = (unsigned)u << 16;
    return v.f;
}
}

// ---- Kernel 1: k1 = relu(W_k1 x + b), v = W_v x + b  via bf16 MFMA ----
// Outputs PX-MAJOR bf16: k1pm/vpm [b][hw][32]. Block 0 also converts o_w -> bf16.
__global__ __launch_bounds__(256) void ns_k1v(
    const float* __restrict__ x,
    const float* __restrict__ k1_w, const float* __restrict__ k1_b,
    const float* __restrict__ v_w,  const float* __restrict__ v_b,
    const float* __restrict__ o_w,
    unsigned short* __restrict__ k1pm, unsigned short* __restrict__ vpm,
    unsigned short* __restrict__ owbf)
{
    constexpr int LP = 72;                      // row stride (shorts): 144 B
    __shared__ short w_bf[64][LP];              // chunk of W (64 o x 64 ch)
    __shared__ short x_bf[128][LP];             // chunk of X (128 px x 64 ch)

    const int tid = threadIdx.x;
    const int l   = tid & 63;
    const int li  = l & 15;
    const int lk  = l >> 4;
    const int wv  = __builtin_amdgcn_readfirstlane(tid >> 6);

    // one-time o_w -> bf16 (owbf consumed only after this kernel completes)
    if (blockIdx.x == 0) {
        for (int i = tid * 4; i < Cc * CVc; i += 256 * 4) {
            const float4 f = *(const float4*)(o_w + i);
            const unsigned a = (unsigned)f2bf(f.x) | ((unsigned)f2bf(f.y) << 16);
            const unsigned c = (unsigned)f2bf(f.z) | ((unsigned)f2bf(f.w) << 16);
            *(uint2*)(owbf + i) = make_uint2(a, c);
        }
    }

    const int flat0 = blockIdx.x * 128;
    const int b  = flat0 / HWc;
    const int pp = flat0 - b * HWc;
    const float* xb = x + (size_t)b * Cc * HWc + pp;

    const int sp2 = (tid & 63) * 2;             // X staging: pixel pair base
    const int scg = tid >> 6;                   // X staging: ch group (16 ch)
    const int so   = tid & 63;                  // W staging: output row
    const int swc0 = (tid >> 6) * 16;
    const float* wsrc = (so < 32) ? (k1_w + (size_t)so * Cc)
                                  : (v_w + (size_t)(so - 32) * Cc);

    f32x4 acc[8];
    const f32x4 zero = {0.f, 0.f, 0.f, 0.f};
#pragma unroll
    for (int i = 0; i < 8; ++i) acc[i] = zero;

    for (int c0 = 0; c0 < Cc; c0 += 64) {
        __syncthreads();
        // ---- stage W chunk ----
        {
            alignas(16) short tmp[16];
#pragma unroll
            for (int f = 0; f < 4; ++f) {
                const float4 fv = *(const float4*)(wsrc + c0 + swc0 + f * 4);
                tmp[f*4+0] = f2bf(fv.x); tmp[f*4+1] = f2bf(fv.y);
                tmp[f*4+2] = f2bf(fv.z); tmp[f*4+3] = f2bf(fv.w);
            }
            *(s16x8*)&w_bf[so][swc0]     = *(const s16x8*)&tmp[0];
            *(s16x8*)&w_bf[so][swc0 + 8] = *(const s16x8*)&tmp[8];
        }
        // ---- stage X chunk: 2 px x 16 ch per thread, 16 batched float2 loads ----
        {
            float2 xv2[16];
#pragma unroll
            for (int cq = 0; cq < 16; ++cq)
                xv2[cq] = *(const float2*)(xb + (size_t)(c0 + scg * 16 + cq) * HWc + sp2);
            alignas(16) short ta[16], tb[16];
#pragma unroll
            for (int cq = 0; cq < 16; ++cq) {
                ta[cq] = f2bf(xv2[cq].x);
                tb[cq] = f2bf(xv2[cq].y);
            }
            *(s16x8*)&x_bf[sp2    ][scg * 16]     = *(const s16x8*)&ta[0];
            *(s16x8*)&x_bf[sp2    ][scg * 16 + 8] = *(const s16x8*)&ta[8];
            *(s16x8*)&x_bf[sp2 + 1][scg * 16]     = *(const s16x8*)&tb[0];
            *(s16x8*)&x_bf[sp2 + 1][scg * 16 + 8] = *(const s16x8*)&tb[8];
        }
        __syncthreads();

#pragma unroll
        for (int ks = 0; ks < 2; ++ks) {
            const s16x8 ar = *(const s16x8*)&w_bf[wv * 16 + li][ks * 32 + lk * 8];
            const bf16x8 af = __builtin_bit_cast(bf16x8, ar);
#pragma unroll
            for (int pt = 0; pt < 8; ++pt) {
                const s16x8 br = *(const s16x8*)&x_bf[pt * 16 + li][ks * 32 + lk * 8];
                acc[pt] = __builtin_amdgcn_mfma_f32_16x16x32_bf16(
                    af, __builtin_bit_cast(bf16x8, br), acc[pt], 0, 0, 0);
            }
        }
    }

    const bool is_k = wv < 2;
    const int obase = wv * 16 + lk * 4;
    const int chq = is_k ? obase : obase - 32;
    float bias[4];
#pragma unroll
    for (int r = 0; r < 4; ++r)
        bias[r] = is_k ? k1_b[obase + r] : v_b[obase + r - 32];
    unsigned short* dstb = is_k ? k1pm : vpm;

#pragma unroll
    for (int pt = 0; pt < 8; ++pt) {
        const size_t row = (size_t)b * HWc + pp + pt * 16 + li;
        float v0 = acc[pt][0] + bias[0], v1 = acc[pt][1] + bias[1];
        float v2 = acc[pt][2] + bias[2], v3 = acc[pt][3] + bias[3];
        if (is_k) {
            v0 = fmaxf(v0, 0.f); v1 = fmaxf(v1, 0.f);
            v2 = fmaxf(v2, 0.f); v3 = fmaxf(v3, 0.f);
        }
        const unsigned p01 = (unsigned)f2bf(v0) | ((unsigned)f2bf(v1) << 16);
        const unsigned p23 = (unsigned)f2bf(v2) | ((unsigned)f2bf(v3) << 16);
        *(uint2*)(dstb + row * 32 + chq) = make_uint2(p01, p23);
    }
}

// ---- Kernel 2 (fused): y-gen (LDS-resident y) + out conv + residual.
//      256 thr / 128 px, 1024 blocks. dlds now bf16 (16 KB) -> LDS ~21.9 KB,
//      __launch_bounds__(256,5) -> 5 blocks/CU (20 waves). Barrier-free
//      per-wave transpose retained; bank-optimal XOR swizzles. ----
__global__ __launch_bounds__(256, 5) void ns_yoc(
    const float* __restrict__ x,
    const unsigned short* __restrict__ k1pm,
    const unsigned short* __restrict__ vpm,
    const float* __restrict__ dw_w, const float* __restrict__ dw_b,
    const float* __restrict__ k3_w, const float* __restrict__ k3_b,
    const unsigned short* __restrict__ owbf, const float* __restrict__ o_b,
    float* __restrict__ out)
{
    // pool: phase 1 = plds (9216 B) + ylds (10240 B); phase 2 = dlds bf16 (16384 B)
    __shared__ alignas(16) unsigned char pool[19456];
    float* plds = (float*)pool;                      // [2][9][128]
    short* ylds = (short*)(pool + 9216);             // [128][40]
    short* dl   = (short*)pool;                      // [64][128] bf16 (phase 2)
    __shared__ float dwt[KKc][CKc];
    __shared__ float k3s[KKc][CKc];
    __shared__ float dwbs[CKc];
    __shared__ float k3bs[KKc];

    const int tid = threadIdx.x;
    for (int idx = tid; idx < CKc * KKc; idx += 256) {
        const int ck = idx / KKc, kk = idx - ck * KKc;
        dwt[kk][ck] = dw_w[idx];
        ((float*)k3s)[idx] = k3_w[idx];
    }
    if (tid < CKc) dwbs[tid] = dw_b[tid];
    if (tid < KKc) k3bs[tid] = k3_b[tid];
    __syncthreads();

    // XCD-bijective swizzle: nwg = 1024 = 8 * 128 -> chunk = 128
    const int bid = blockIdx.x;
    const int swz = (bid & 7) * 128 + (bid >> 3);

    const int pxi  = tid & 127;                 // pixel within row
    const int half = tid >> 7;                  // channel half
    const int cb   = half * 16;

    const int flat0 = swz * 128;
    const int b   = flat0 / HWc;
    const int row = flat0 - b * HWc;            // px offset of this image row
    const int h   = row >> 7;                   // Wc == 128
    const int w   = pxi;

    const unsigned short* k1b = k1pm + (size_t)b * HWc * 32;
    const unsigned short* vb  = vpm  + (size_t)b * HWc * 32;

    // ---- phase 1a: depthwise 3x3, own 16 channels ----
    float t[16];
#pragma unroll
    for (int e = 0; e < 16; ++e) t[e] = dwbs[cb + e];
#pragma unroll
    for (int i = 0; i < 3; ++i) {
        const int hh = h + i - 1;
#pragma unroll
        for (int j = 0; j < 3; ++j) {
            const int ww = w + j - 1;
            if (hh < 0 || hh >= Hc || ww < 0 || ww >= Wc) continue;
            const unsigned short* kr = k1b + (size_t)(hh * Wc + ww) * 32 + cb;
            const int ij = i * 3 + j;
#pragma unroll
            for (int qv = 0; qv < 2; ++qv) {
                const bf16x8 kv = __builtin_bit_cast(bf16x8, *(const s16x8*)(kr + qv * 8));
#pragma unroll
                for (int e = 0; e < 8; ++e)
                    t[qv * 8 + e] = fmaf((float)kv[e], dwt[ij][cb + qv * 8 + e],
                                         t[qv * 8 + e]);
            }
        }
    }

    // ---- phase 1b: partial 1x1 CK->9; exchange via plds ----
#pragma unroll
    for (int kk = 0; kk < KKc; ++kk) {
        float a = (half == 0) ? k3bs[kk] : 0.f;
#pragma unroll
        for (int e = 0; e < 16; ++e)
            a = fmaf(k3s[kk][cb + e], t[e], a);
        plds[(half * KKc + kk) * 128 + pxi] = a;
    }
    __syncthreads();

    float logit[KKc];
#pragma unroll
    for (int kk = 0; kk < KKc; ++kk)
        logit[kk] = plds[kk * 128 + pxi] + plds[(KKc + kk) * 128 + pxi];

    float m = logit[0];
#pragma unroll
    for (int kk = 1; kk < KKc; ++kk) m = fmaxf(m, logit[kk]);
    float s = 0.f;
#pragma unroll
    for (int kk = 0; kk < KKc; ++kk) { logit[kk] = expf(logit[kk] - m); s += logit[kk]; }
    const float inv = 1.f / s;
#pragma unroll
    for (int kk = 0; kk < KKc; ++kk) logit[kk] *= inv;

    // ---- phase 1c: unfold-aggregate, own 16 v-channels ----
    float yv[16];
#pragma unroll
    for (int e = 0; e < 16; ++e) yv[e] = 0.f;
#pragma unroll
    for (int i = 0; i < 3; ++i) {
        const int hh = h + i - 1;
#pragma unroll
        for (int j = 0; j < 3; ++j) {
            const int ww = w + j - 1;
            if (hh < 0 || hh >= Hc || ww < 0 || ww >= Wc) continue;
            const unsigned short* vr = vb + (size_t)(hh * Wc + ww) * 32 + cb;
            const float wv = logit[i * 3 + j];
#pragma unroll
            for (int qv = 0; qv < 2; ++qv) {
                const bf16x8 vv = __builtin_bit_cast(bf16x8, *(const s16x8*)(vr + qv * 8));
#pragma unroll
                for (int e = 0; e < 8; ++e)
                    yv[qv * 8 + e] = fmaf(wv, (float)vv[e], yv[qv * 8 + e]);
            }
        }
    }

    // y -> ylds bf16 [px][40] (own half: 32 B)
    {
        alignas(16) short ybf[16];
#pragma unroll
        for (int e = 0; e < 16; ++e) ybf[e] = (short)f2bf(yv[e]);
        short* yo = ylds + pxi * 40 + cb;
        *(float4*)(yo)     = *(const float4*)&ybf[0];
        *(float4*)(yo + 8) = *(const float4*)&ybf[8];
    }
    __syncthreads();                            // ylds complete

    // ---- phase 2: out conv + residual (y from LDS, bf16 dlds transpose) ----
    const int wv2 = tid >> 6;                   // wave 0..3
    const int l   = tid & 63;
    const int li  = l & 15;
    const int lk  = l >> 4;

    bf16x8 yfrag[8];
#pragma unroll
    for (int pt = 0; pt < 8; ++pt)
        yfrag[pt] = __builtin_bit_cast(bf16x8,
            *(const s16x8*)(ylds + (pt * 16 + li) * 40 + lk * 8));
    __syncthreads();                            // all yfrags read; dl may clobber

    const float* xb0 = x + (size_t)b * Cc * HWc + row;
    float* ob0 = out + (size_t)b * Cc * HWc + row;

    for (int pass = 0; pass < 4; ++pass) {
        const int och0 = pass * 64;

        // phase A: 8 MFMAs, D -> own LDS rows as bf16 (barrier-free transpose)
        const int rowA = wv2 * 16 + li;
        const bf16x8 wfrag = __builtin_bit_cast(bf16x8,
            *(const s16x8*)(owbf + (size_t)(och0 + rowA) * 32 + lk * 8));
        short* dro = dl + rowA * 128;
#pragma unroll
        for (int pt = 0; pt < 8; ++pt) {
            f32x4 acc = {0.f, 0.f, 0.f, 0.f};
            acc = __builtin_amdgcn_mfma_f32_16x16x32_bf16(yfrag[pt], wfrag, acc, 0, 0, 0);
            const int col = (pt * 16 + lk * 4) ^ (li << 2);   // shorts, 8B-aligned
            const unsigned p01 = (unsigned)f2bf(acc[0]) | ((unsigned)f2bf(acc[1]) << 16);
            const unsigned p23 = (unsigned)f2bf(acc[2]) | ((unsigned)f2bf(acc[3]) << 16);
            *(uint2*)(dro + col) = make_uint2(p01, p23);
        }

        // phase B: batched 512 B-contiguous x-loads, bf16 LDS read-back, store
        float2 xvv[16];
#pragma unroll
        for (int r = 0; r < 16; ++r) {
            const int och = och0 + wv2 * 16 + r;
            xvv[r] = *(const float2*)(xb0 + (size_t)och * HWc + l * 2);
        }
#pragma unroll
        for (int r = 0; r < 16; ++r) {
            const int rw = wv2 * 16 + r;
            const int och = och0 + rw;
            const float bi = o_b[och];
            const int col = (l * 2) ^ ((rw & 15) << 2);        // shorts, 4B-aligned
            const unsigned dvu = *(const unsigned*)(dl + rw * 128 + col);
            float2 ov = { xvv[r].x + bf2f((unsigned short)(dvu & 0xffff)) + bi,
                          xvv[r].y + bf2f((unsigned short)(dvu >> 16)) + bi };
            *(float2*)(ob0 + (size_t)och * HWc + l * 2) = ov;
        }
    }
}

extern "C" void kernel_launch(void* const* d_in, const int* in_sizes, int n_in,
                              void* d_out, int out_size, void* d_ws, size_t ws_size,
                              hipStream_t stream)
{
    const float* x    = (const float*)d_in[0];
    const float* k1_w = (const float*)d_in[1];
    const float* k1_b = (const float*)d_in[2];
    const float* dw_w = (const float*)d_in[3];
    const float* dw_b = (const float*)d_in[4];
    const float* k3_w = (const float*)d_in[5];
    const float* k3_b = (const float*)d_in[6];
    const float* v_w  = (const float*)d_in[7];
    const float* v_b  = (const float*)d_in[8];
    const float* o_w  = (const float*)d_in[9];
    const float* o_b  = (const float*)d_in[10];
    float* out = (float*)d_out;

    // workspace: k1pm (8.4MB) | vpm (8.4MB) | owbf (16KB), bf16
    unsigned short* k1pm = (unsigned short*)d_ws;
    unsigned short* vpm  = k1pm + (size_t)Bc * HWc * 32;
    unsigned short* owbf = vpm  + (size_t)Bc * HWc * 32;

    const int npx = Bc * HWc;                   // 131072

    ns_k1v<<<dim3(npx / 128), dim3(256), 0, stream>>>(x, k1_w, k1_b, v_w, v_b, o_w,
                                                      k1pm, vpm, owbf);
    ns_yoc<<<dim3(npx / 128), dim3(256), 0, stream>>>(x, k1pm, vpm, dw_w, dw_b,
                                                      k3_w, k3_b, owbf, o_b, out);
}